// Round 5
// baseline (34672.458 us; speedup 1.0000x reference)
//
#include <hip/hip_runtime.h>
#include <hip/hip_bf16.h>

#define T_LEN 2048
#define NG    8192   // 2 dirs * 4H

typedef __attribute__((ext_vector_type(8))) short short8;
typedef __attribute__((ext_vector_type(4))) float f32x4;
typedef __attribute__((ext_vector_type(2))) float f32x2;
typedef unsigned long long ull;

__device__ __forceinline__ unsigned short f2b(float f) {
  union { float f; unsigned u; } a; a.f = f;
  unsigned r = a.u + 0x7fffu + ((a.u >> 16) & 1u);   // RNE to bf16
  return (unsigned short)(r >> 16);
}

__device__ __forceinline__ float fast_tanh(float x) {
  x = fminf(15.f, fmaxf(-15.f, x));
  float e = __expf(2.f * x);
  return (e - 1.f) / (e + 1.f);
}

// embeds = concat(sentence, emb_speech[tags]) -> bf16 [2048][1088]
__global__ void embed_k(const float* __restrict__ sent, const int* __restrict__ tags,
                        const float* __restrict__ emb, unsigned short* __restrict__ out) {
  int idx = blockIdx.x * 256 + threadIdx.x;          // exactly 2048*1088 threads
  int t = idx / 1088, c = idx - t * 1088;
  float v = (c < 1024) ? sent[t * 1024 + c] : emb[tags[t] * 64 + (c - 1024)];
  out[idx] = f2b(v);
}

__global__ void cvt_k(const float* __restrict__ in, unsigned short* __restrict__ out, int n4) {
  int i = blockIdx.x * 256 + threadIdx.x;
  if (i < n4) {
    float4 v = ((const float4*)in)[i];
    unsigned short* o = out + (size_t)i * 4;
    o[0] = f2b(v.x); o[1] = f2b(v.y); o[2] = f2b(v.z); o[3] = f2b(v.w);
  }
}

__global__ void bias_k(const float* __restrict__ a, const float* __restrict__ b,
                       float* __restrict__ o) {
  int i = blockIdx.x * 256 + threadIdx.x;            // 8192
  o[i] = a[i] + b[i];
}

// C[2048][N] = A[2048][K](bf16) * B[N][K](bf16)^T + bsum[N]   (fp32 accumulate)
__global__ __launch_bounds__(256) void gemm_bf16(
    const unsigned short* __restrict__ A, const unsigned short* __restrict__ B,
    const float* __restrict__ bsum, float* __restrict__ C, int N, int K) {
  const int lane = threadIdx.x & 63;
  const int wv   = threadIdx.x >> 6;
  const int n0 = blockIdx.x * 64;
  const int m0 = blockIdx.y * 64 + wv * 16;
  const unsigned short* ap = A + (size_t)(m0 + (lane & 15)) * K + ((lane >> 4) * 8);
  const unsigned short* bp = B + (size_t)(n0 + (lane & 15)) * K + ((lane >> 4) * 8);
  f32x4 ac0 = {0.f, 0.f, 0.f, 0.f}, ac1 = ac0, ac2 = ac0, ac3 = ac0;
  for (int k = 0; k < K; k += 32) {
    short8 av = *(const short8*)(ap + k);
    short8 b0 = *(const short8*)(bp + k);
    short8 b1 = *(const short8*)(bp + (size_t)16 * K + k);
    short8 b2 = *(const short8*)(bp + (size_t)32 * K + k);
    short8 b3 = *(const short8*)(bp + (size_t)48 * K + k);
    ac0 = __builtin_amdgcn_mfma_f32_16x16x32_bf16(av, b0, ac0, 0, 0, 0);
    ac1 = __builtin_amdgcn_mfma_f32_16x16x32_bf16(av, b1, ac1, 0, 0, 0);
    ac2 = __builtin_amdgcn_mfma_f32_16x16x32_bf16(av, b2, ac2, 0, 0, 0);
    ac3 = __builtin_amdgcn_mfma_f32_16x16x32_bf16(av, b3, ac3, 0, 0, 0);
  }
  const int cr = m0 + (lane >> 4) * 4;
  const int cc = n0 + (lane & 15);
#pragma unroll
  for (int i = 0; i < 4; ++i) {
    C[(size_t)(cr + i) * N + cc +  0] = ac0[i] + bsum[cc +  0];
    C[(size_t)(cr + i) * N + cc + 16] = ac1[i] + bsum[cc + 16];
    C[(size_t)(cr + i) * N + cc + 32] = ac2[i] + bsum[cc + 32];
    C[(size_t)(cr + i) * N + cc + 48] = ac3[i] + bsum[cc + 48];
  }
}

// Persistent bidirectional LSTM scan, latency-optimized h exchange.
// grid = 64 blocks x 1024 thr (16 waves) — MERGED-PAIR geometry. 32 blocks
// per direction; each block owns 32 hidden units, each wave 2 units (lanes
// 0,1 carry the cell state). Rationale (R4 post-mortem): poll-round traffic
// and compute micro-structure are saturated (R1 2x8B-load poll == R4 16B
// poll within noise); the residual ~1.5 us/step of the 2.5 us step is the
// rendezvous segment. Halving the barrier-domain count (128->64) and the
// per-line poll fan-in (each hbuf slot now polled by half as many blocks)
// attacks max-over-participants jitter and MALL queueing with ZERO change
// to the per-wave math: still 2 units/wave, same weight layout, same
// butterfly reduce. Poll round is now the minimum possible: ONE 8B agent
// atomic load per lane (16 waves x 64 lanes = 1024 slots exactly).
// VGPR=88 <= 128 -> 4 waves/SIMD, one 1024-thr block per CU.
// Cross-block h exchange: tagged 64-bit RELAXED agent atomics,
// word = (tag<<32)|f32bits(h) — tag match IS the sync, no fences. Parity
// double-buffer: a producer publishes h_{t+1} only after all its block's
// waves staged h_t to LDS (the pre-compute barrier orders this), so the
// parity-(t&1) slots are dead before any block can overwrite them at t+2.
__global__ __launch_bounds__(1024) void lstm_scan(
    const float* __restrict__ xp,     // [T][8192] = dir*4096 + gate*1024 + j
    const float* __restrict__ whh,    // [2][4096][1024] fp32
    unsigned short* __restrict__ outb,// [T][2048] bf16 or null
    float* __restrict__ outf,         // [T][2048] f32 or null
    ull* __restrict__ hbuf) {         // [2 dir][2 parity][1024] tagged slots
  __shared__ float hsh[2][1024];             // 8 KB parity double-buffer
  const int tid  = threadIdx.x;
  const int lane = tid & 63;
  const int wv   = tid >> 6;                 // 0..15
  const int dir  = blockIdx.x >> 5;          // 32 blocks per direction
  const int bb   = blockIdx.x & 31;
  const int u0   = bb * 32 + wv * 2;         // wave's first hidden unit
  const int jj   = u0 + lane;                // unit id (valid for lanes 0,1)

  ull* hb = hbuf + dir * 2048;
  if (lane < 2)   // publish h^0 = 0 with tag 1 (parity 0) ASAP
    __hip_atomic_store(&hb[jj], ((ull)1 << 32), __ATOMIC_RELAXED, __HIP_MEMORY_SCOPE_AGENT);

  // weights -> registers, fp32: w[u][g][m] = cols (2*lane+128m, 2*lane+128m+1)
  // of row (dir, g*1024 + u0+u). Coalesced dwordx2 loads. (Allocator may
  // spill part of this to scratch — R1-R3 A/B proved that traffic is fully
  // hidden under the poll wait; bf16-resident variant was SLOWER.)
  f32x2 w[2][4][8];
#pragma unroll
  for (int u = 0; u < 2; ++u)
#pragma unroll
    for (int g = 0; g < 4; ++g) {
      const f32x2* wr = (const f32x2*)(whh + ((size_t)dir * 4096 + g * 1024 + u0 + u) * 1024);
#pragma unroll
      for (int m = 0; m < 8; ++m) {
        f32x2 tw = wr[lane + 64 * m];
        asm volatile("" : "+v"(tw));         // opaque def: no remat
        w[u][g][m] = tw;
      }
    }

  const int s0 = wv * 64 + lane;             // this wave's single poll slot/lane
  float c_state = 0.f;

  for (int t = 0; t < T_LEN; ++t) {
    const int tt  = dir ? (T_LEN - 1 - t) : t;
    const int par = t & 1;

    // xp prefetch: issue before the poll so L2/L3 latency hides under it.
    // Unconditional (all-lane) loads keep them out of the lane<2 branch;
    // lanes>=2 read in-bounds-of-workspace garbage and discard it.
    const size_t xb = (size_t)tt * NG + dir * 4096 + jj;
    float xg0 = xp[xb];
    float xg1 = xp[xb + 1024];
    float xg2 = xp[xb + 2048];
    float xg3 = xp[xb + 3072];

    // distributed poll: one 8B agent load per lane covers all 1024 slots
    const ull* hp = hb + (par ? 1024 : 0);
    const unsigned tagw = (unsigned)(t + 1);
    ull v0;
    for (;;) {
      v0 = __hip_atomic_load(hp + s0, __ATOMIC_RELAXED, __HIP_MEMORY_SCOPE_AGENT);
      unsigned bad = ((unsigned)(v0 >> 32)) ^ tagw;
      if (__ballot(bad != 0) == 0ull) break;   // wave-uniform exit
    }
    hsh[par][s0] = __uint_as_float((unsigned)v0);
    __syncthreads();

    // h as float2 pairs matching the weight register layout
    f32x2 h2[8];
    const f32x2* hv = (const f32x2*)hsh[par];
#pragma unroll
    for (int m = 0; m < 8; ++m) h2[m] = hv[lane + 64 * m];

    // 8 accumulator chains (2 units x 4 gates), v_pk_fma_f32
    f32x2 acc[2][4];
#pragma unroll
    for (int u = 0; u < 2; ++u)
#pragma unroll
      for (int g = 0; g < 4; ++g) {
        f32x2 a = {0.f, 0.f};
#pragma unroll
        for (int m = 0; m < 8; ++m)
          a = __builtin_elementwise_fma(w[u][g][m], h2[m], a);
        acc[u][g] = a;
      }

    float p[8];
#pragma unroll
    for (int u = 0; u < 2; ++u)
#pragma unroll
      for (int g = 0; g < 4; ++g)
        p[u * 4 + g] = acc[u][g].x + acc[u][g].y;

    // exchange-halving butterfly over 8 values then full reduce:
    // value v = u*4+g ends (replicated) on lane u + 2*(g>>1) + 4*(g&1)
    float r4[4];
    {
      const bool b0 = (lane & 1) != 0;
#pragma unroll
      for (int i = 0; i < 4; ++i) {
        float send = b0 ? p[i] : p[4 + i];
        float keep = b0 ? p[4 + i] : p[i];
        r4[i] = keep + __shfl_xor(send, 1, 64);
      }
    }
    float r2[2];
    {
      const bool b1 = (lane & 2) != 0;
#pragma unroll
      for (int i = 0; i < 2; ++i) {
        float send = b1 ? r4[i] : r4[2 + i];
        float keep = b1 ? r4[2 + i] : r4[i];
        r2[i] = keep + __shfl_xor(send, 2, 64);
      }
    }
    float red;
    {
      const bool b2 = (lane & 4) != 0;
      float send = b2 ? r2[0] : r2[1];
      float keep = b2 ? r2[1] : r2[0];
      red = keep + __shfl_xor(send, 4, 64);
    }
    red += __shfl_xor(red, 8, 64);
    red += __shfl_xor(red, 16, 64);
    red += __shfl_xor(red, 32, 64);

    // gather the 4 gates of unit u onto lane u (u = 0,1)
    float gi = red;                             // g=0 at lane u
    float gf = __shfl(red, lane + 4, 64);       // g=1 at lane u+4
    float gg = __shfl(red, lane + 2, 64);       // g=2 at lane u+2
    float go = __shfl(red, lane + 6, 64);       // g=3 at lane u+6

    if (lane < 2) {
      gi += xg0; gf += xg1; gg += xg2; go += xg3;
      float i_ = 1.f / (1.f + __expf(-gi));
      float f_ = 1.f / (1.f + __expf(-gf));
      float g_ = fast_tanh(gg);
      float o_ = 1.f / (1.f + __expf(-go));
      c_state = f_ * c_state + i_ * g_;
      float hn = o_ * fast_tanh(c_state);
      ull packed = ((ull)(unsigned)(t + 2) << 32) | (ull)__float_as_uint(hn);
      __hip_atomic_store(&hb[(((t + 1) & 1) ? 1024 : 0) + jj], packed,
                         __ATOMIC_RELAXED, __HIP_MEMORY_SCOPE_AGENT);
      const int col = dir * 1024 + jj;
      if (outb) outb[(size_t)tt * 2048 + col] = f2b(hn);
      if (outf) outf[(size_t)tt * 2048 + col] = hn;
    }
  }
}

// out[t][tag] = h1[t]·w_out[tag] + b_out[tag]
__global__ void out_proj(const float* __restrict__ h1, const float* __restrict__ w,
                         const float* __restrict__ b, float* __restrict__ out) {
  int t = blockIdx.x;
  int tag = threadIdx.x;
  if (tag >= 50) return;
  const float4* hp = (const float4*)(h1 + (size_t)t * 2048);
  const float4* wp = (const float4*)(w + (size_t)tag * 2048);
  float acc = 0.f;
#pragma unroll 8
  for (int i = 0; i < 512; ++i) {
    float4 a = hp[i], c = wp[i];
    acc += a.x * c.x + a.y * c.y + a.z * c.z + a.w * c.w;
  }
  out[t * 50 + tag] = acc + b[tag];
}

extern "C" void kernel_launch(void* const* d_in, const int* in_sizes, int n_in,
                              void* d_out, int out_size, void* d_ws, size_t ws_size,
                              hipStream_t stream) {
  (void)in_sizes; (void)n_in; (void)out_size; (void)ws_size;
  const float* sent  = (const float*)d_in[0];
  const int*   stags = (const int*)  d_in[1];
  const float* embsp = (const float*)d_in[2];
  const float* wih0  = (const float*)d_in[3];
  const float* whh0  = (const float*)d_in[4];
  const float* bih0  = (const float*)d_in[5];
  const float* bhh0  = (const float*)d_in[6];
  const float* wih1  = (const float*)d_in[7];
  const float* whh1  = (const float*)d_in[8];
  const float* bih1  = (const float*)d_in[9];
  const float* bhh1  = (const float*)d_in[10];
  const float* wout  = (const float*)d_in[11];
  const float* bout  = (const float*)d_in[12];
  float* out = (float*)d_out;

  char* ws = (char*)d_ws;
  size_t off = 0;
  auto take = [&](size_t bytes) { char* p = ws + off; off += (bytes + 255) & ~(size_t)255; return p; };
  float*          xp    = (float*)         take((size_t)2048 * 8192 * 4);  // shared by both layers
  unsigned short* embB  = (unsigned short*)take((size_t)2048 * 1088 * 2);
  unsigned short* w0B   = (unsigned short*)take((size_t)8192 * 1088 * 2);
  unsigned short* w1B   = (unsigned short*)take((size_t)8192 * 2048 * 2);
  unsigned short* h0B   = (unsigned short*)take((size_t)2048 * 2048 * 2);
  float*          h1F   = (float*)         take((size_t)2048 * 2048 * 4);
  float*          bs0   = (float*)         take(8192 * 4);
  float*          bs1   = (float*)         take(8192 * 4);
  ull*            hbufA = (ull*)           take(2 * 2 * 1024 * 8);
  ull*            hbufB = (ull*)           take(2 * 2 * 1024 * 8);
  // harness poisons ws to 0xAA -> stale tags are 0xAAAAAAAA, never a live
  // tag (1..2050), so hbuf needs no zero-init pass.

  embed_k<<<8704, 256, 0, stream>>>(sent, stags, embsp, embB);
  cvt_k<<<8704, 256, 0, stream>>>(wih0, w0B, 2228224);    // 8192*1088/4
  cvt_k<<<16384, 256, 0, stream>>>(wih1, w1B, 4194304);   // 8192*2048/4
  bias_k<<<32, 256, 0, stream>>>(bih0, bhh0, bs0);
  bias_k<<<32, 256, 0, stream>>>(bih1, bhh1, bs1);

  dim3 gg(128, 32);
  gemm_bf16<<<gg, 256, 0, stream>>>(embB, w0B, bs0, xp, 8192, 1088);
  lstm_scan<<<64, 1024, 0, stream>>>(xp, whh0, h0B, nullptr, hbufA);
  gemm_bf16<<<gg, 256, 0, stream>>>(h0B, w1B, bs1, xp, 8192, 2048);
  lstm_scan<<<64, 1024, 0, stream>>>(xp, whh1, nullptr, h1F, hbufB);
  out_proj<<<2048, 64, 0, stream>>>(h1F, wout, bout, out);
}

// Round 7
// 8908.331 us; speedup vs baseline: 3.8921x; 3.8921x over previous
//
#include <hip/hip_runtime.h>
#include <hip/hip_bf16.h>

#define T_LEN 2048
#define NG    8192   // 2 dirs * 4H

typedef __attribute__((ext_vector_type(8))) short short8;
typedef __attribute__((ext_vector_type(4))) float f32x4;
typedef __attribute__((ext_vector_type(2))) float f32x2;
typedef unsigned long long ull;

__device__ __forceinline__ unsigned short f2b(float f) {
  union { float f; unsigned u; } a; a.f = f;
  unsigned r = a.u + 0x7fffu + ((a.u >> 16) & 1u);   // RNE to bf16
  return (unsigned short)(r >> 16);
}

__device__ __forceinline__ float fast_tanh(float x) {
  x = fminf(15.f, fmaxf(-15.f, x));
  float e = __expf(2.f * x);
  return (e - 1.f) / (e + 1.f);
}

// embeds = concat(sentence, emb_speech[tags]) -> bf16 [2048][1088]
__global__ void embed_k(const float* __restrict__ sent, const int* __restrict__ tags,
                        const float* __restrict__ emb, unsigned short* __restrict__ out) {
  int idx = blockIdx.x * 256 + threadIdx.x;          // exactly 2048*1088 threads
  int t = idx / 1088, c = idx - t * 1088;
  float v = (c < 1024) ? sent[t * 1024 + c] : emb[tags[t] * 64 + (c - 1024)];
  out[idx] = f2b(v);
}

__global__ void cvt_k(const float* __restrict__ in, unsigned short* __restrict__ out, int n4) {
  int i = blockIdx.x * 256 + threadIdx.x;
  if (i < n4) {
    float4 v = ((const float4*)in)[i];
    unsigned short* o = out + (size_t)i * 4;
    o[0] = f2b(v.x); o[1] = f2b(v.y); o[2] = f2b(v.z); o[3] = f2b(v.w);
  }
}

__global__ void bias_k(const float* __restrict__ a, const float* __restrict__ b,
                       float* __restrict__ o) {
  int i = blockIdx.x * 256 + threadIdx.x;            // 8192
  o[i] = a[i] + b[i];
}

// C[2048][N] = A[2048][K](bf16) * B[N][K](bf16)^T + bsum[N]   (fp32 accumulate)
__global__ __launch_bounds__(256) void gemm_bf16(
    const unsigned short* __restrict__ A, const unsigned short* __restrict__ B,
    const float* __restrict__ bsum, float* __restrict__ C, int N, int K) {
  const int lane = threadIdx.x & 63;
  const int wv   = threadIdx.x >> 6;
  const int n0 = blockIdx.x * 64;
  const int m0 = blockIdx.y * 64 + wv * 16;
  const unsigned short* ap = A + (size_t)(m0 + (lane & 15)) * K + ((lane >> 4) * 8);
  const unsigned short* bp = B + (size_t)(n0 + (lane & 15)) * K + ((lane >> 4) * 8);
  f32x4 ac0 = {0.f, 0.f, 0.f, 0.f}, ac1 = ac0, ac2 = ac0, ac3 = ac0;
  for (int k = 0; k < K; k += 32) {
    short8 av = *(const short8*)(ap + k);
    short8 b0 = *(const short8*)(bp + k);
    short8 b1 = *(const short8*)(bp + (size_t)16 * K + k);
    short8 b2 = *(const short8*)(bp + (size_t)32 * K + k);
    short8 b3 = *(const short8*)(bp + (size_t)48 * K + k);
    ac0 = __builtin_amdgcn_mfma_f32_16x16x32_bf16(av, b0, ac0, 0, 0, 0);
    ac1 = __builtin_amdgcn_mfma_f32_16x16x32_bf16(av, b1, ac1, 0, 0, 0);
    ac2 = __builtin_amdgcn_mfma_f32_16x16x32_bf16(av, b2, ac2, 0, 0, 0);
    ac3 = __builtin_amdgcn_mfma_f32_16x16x32_bf16(av, b3, ac3, 0, 0, 0);
  }
  const int cr = m0 + (lane >> 4) * 4;
  const int cc = n0 + (lane & 15);
#pragma unroll
  for (int i = 0; i < 4; ++i) {
    C[(size_t)(cr + i) * N + cc +  0] = ac0[i] + bsum[cc +  0];
    C[(size_t)(cr + i) * N + cc + 16] = ac1[i] + bsum[cc + 16];
    C[(size_t)(cr + i) * N + cc + 32] = ac2[i] + bsum[cc + 32];
    C[(size_t)(cr + i) * N + cc + 48] = ac3[i] + bsum[cc + 48];
  }
}

// Persistent bidirectional LSTM scan, latency-optimized h exchange.
// grid = 128 blocks x 512 thr (8 waves) — R1's proven geometry (R5's 64x1024
// merge regressed 3.2x: compiler capped VGPR=64 for 2-blocks/CU, spilling all
// weights + working set -> ~500 KB/CU/step scratch stream became the critical
// path). Each block owns 16 hidden units, each wave 2 (lanes 0,1 carry c).
// XG PIPELINE (this round's single change): vmcnt is FIFO — the poll's
// atomic-load consume emits s_waitcnt vmcnt(0), which DRAINS any older
// outstanding loads. R1 issued the 4 scattered xp loads right before the
// poll, so every step's first poll round serially absorbed an HBM-stream
// latency (~0.2-0.4 us) before the first tag check. Now xg for step t+1 is
// issued AFTER the poll exit of step t: it has the compute tail + the next
// full rendezvous (~2 us) to complete before the next poll drains vmcnt.
// Consume xg_cur in the pointwise, then swap. t+1 clamped at T_LEN-1 (last
// prefetch is redundant, never OOB).
// DISTRIBUTED POLL: each wave polls its own 128 of the 1024 tagged slots
// (2 coalesced 8B loads/lane/round), stages them into LDS hsh[t&1], one
// __syncthreads, then every wave reads the full h from LDS.
// Cross-block h exchange: tagged 64-bit RELAXED agent atomics,
// word = (tag<<32)|f32bits(h) — tag match IS the sync, no fences. Parity
// double-buffer: a producer publishes h_{t+1} only after all its block's
// waves staged h_t to LDS (the pre-compute barrier orders this), so the
// parity-(t&1) slots are dead before any block can overwrite them at t+2.
__global__ __launch_bounds__(512, 2) void lstm_scan(
    const float* __restrict__ xp,     // [T][8192] = dir*4096 + gate*1024 + j
    const float* __restrict__ whh,    // [2][4096][1024] fp32
    unsigned short* __restrict__ outb,// [T][2048] bf16 or null
    float* __restrict__ outf,         // [T][2048] f32 or null
    ull* __restrict__ hbuf) {         // [2 dir][2 parity][1024] tagged slots
  __shared__ float hsh[2][1024];             // 8 KB parity double-buffer
  const int tid  = threadIdx.x;
  const int lane = tid & 63;
  const int wv   = tid >> 6;                 // 0..7
  const int dir  = blockIdx.x >> 6;          // 64 blocks per direction
  const int bb   = blockIdx.x & 63;
  const int u0   = bb * 16 + wv * 2;         // wave's first hidden unit
  const int jj   = u0 + lane;                // unit id (valid for lanes 0,1)

  ull* hb = hbuf + dir * 2048;
  if (lane < 2)   // publish h^0 = 0 with tag 1 (parity 0) ASAP
    __hip_atomic_store(&hb[jj], ((ull)1 << 32), __ATOMIC_RELAXED, __HIP_MEMORY_SCOPE_AGENT);

  // weights -> registers, fp32: w[u][g][m] = cols (2*lane+128m, 2*lane+128m+1)
  // of row (dir, g*1024 + u0+u). Coalesced dwordx2 loads. (Allocator spills
  // part of this to scratch at VGPR~92 — R1-R3 A/B proved that traffic is
  // fully hidden at this geometry; bf16-resident variant was SLOWER.)
  f32x2 w[2][4][8];
#pragma unroll
  for (int u = 0; u < 2; ++u)
#pragma unroll
    for (int g = 0; g < 4; ++g) {
      const f32x2* wr = (const f32x2*)(whh + ((size_t)dir * 4096 + g * 1024 + u0 + u) * 1024);
#pragma unroll
      for (int m = 0; m < 8; ++m) {
        f32x2 tw = wr[lane + 64 * m];
        asm volatile("" : "+v"(tw));         // opaque def: no remat
        w[u][g][m] = tw;
      }
    }

  const int s0 = wv * 128 + lane;            // this wave's poll slots: s0, s0+64
  float c_state = 0.f;

  // xg prologue: load step-0 inputs (drained by the t=0 poll along with the
  // weight loads — one-time cost).
  float xgc0, xgc1, xgc2, xgc3;
  {
    const size_t xb = (size_t)(dir ? (T_LEN - 1) : 0) * NG + dir * 4096 + jj;
    xgc0 = xp[xb];
    xgc1 = xp[xb + 1024];
    xgc2 = xp[xb + 2048];
    xgc3 = xp[xb + 3072];
  }

  for (int t = 0; t < T_LEN; ++t) {
    const int par = t & 1;

    // distributed poll: wait for tag t+1 on this wave's 128 slots.
    // No older vmem outstanding except long-issued prefetches -> the
    // vmcnt(0) here waits only on the poll loads themselves.
    const ull* hp = hb + (par ? 1024 : 0);
    const unsigned tagw = (unsigned)(t + 1);
    ull v0, v1;
    for (;;) {
      v0 = __hip_atomic_load(hp + s0,      __ATOMIC_RELAXED, __HIP_MEMORY_SCOPE_AGENT);
      v1 = __hip_atomic_load(hp + s0 + 64, __ATOMIC_RELAXED, __HIP_MEMORY_SCOPE_AGENT);
      unsigned bad = (((unsigned)(v0 >> 32)) ^ tagw) | (((unsigned)(v1 >> 32)) ^ tagw);
      if (__ballot(bad != 0) == 0ull) break;   // wave-uniform exit
    }
    hsh[par][s0]      = __uint_as_float((unsigned)v0);
    hsh[par][s0 + 64] = __uint_as_float((unsigned)v1);

    // issue NEXT step's xp loads now: they complete under the compute tail
    // + the next rendezvous, so the next poll's vmcnt(0) drain is free.
    const int tn  = (t + 1 < T_LEN) ? t + 1 : t;
    const int ttn = dir ? (T_LEN - 1 - tn) : tn;
    const size_t xbn = (size_t)ttn * NG + dir * 4096 + jj;
    float xgn0 = xp[xbn];
    float xgn1 = xp[xbn + 1024];
    float xgn2 = xp[xbn + 2048];
    float xgn3 = xp[xbn + 3072];

    __syncthreads();

    // h as float2 pairs matching the weight register layout
    f32x2 h2[8];
    const f32x2* hv = (const f32x2*)hsh[par];
#pragma unroll
    for (int m = 0; m < 8; ++m) h2[m] = hv[lane + 64 * m];

    // 8 accumulator chains (2 units x 4 gates), v_pk_fma_f32
    f32x2 acc[2][4];
#pragma unroll
    for (int u = 0; u < 2; ++u)
#pragma unroll
      for (int g = 0; g < 4; ++g) {
        f32x2 a = {0.f, 0.f};
#pragma unroll
        for (int m = 0; m < 8; ++m)
          a = __builtin_elementwise_fma(w[u][g][m], h2[m], a);
        acc[u][g] = a;
      }

    float p[8];
#pragma unroll
    for (int u = 0; u < 2; ++u)
#pragma unroll
      for (int g = 0; g < 4; ++g)
        p[u * 4 + g] = acc[u][g].x + acc[u][g].y;

    // exchange-halving butterfly over 8 values then full reduce:
    // value v = u*4+g ends (replicated) on lane u + 2*(g>>1) + 4*(g&1)
    float r4[4];
    {
      const bool b0 = (lane & 1) != 0;
#pragma unroll
      for (int i = 0; i < 4; ++i) {
        float send = b0 ? p[i] : p[4 + i];
        float keep = b0 ? p[4 + i] : p[i];
        r4[i] = keep + __shfl_xor(send, 1, 64);
      }
    }
    float r2[2];
    {
      const bool b1 = (lane & 2) != 0;
#pragma unroll
      for (int i = 0; i < 2; ++i) {
        float send = b1 ? r4[i] : r4[2 + i];
        float keep = b1 ? r4[2 + i] : r4[i];
        r2[i] = keep + __shfl_xor(send, 2, 64);
      }
    }
    float red;
    {
      const bool b2 = (lane & 4) != 0;
      float send = b2 ? r2[0] : r2[1];
      float keep = b2 ? r2[1] : r2[0];
      red = keep + __shfl_xor(send, 4, 64);
    }
    red += __shfl_xor(red, 8, 64);
    red += __shfl_xor(red, 16, 64);
    red += __shfl_xor(red, 32, 64);

    // gather the 4 gates of unit u onto lane u (u = 0,1)
    float gi = red;                             // g=0 at lane u
    float gf = __shfl(red, lane + 4, 64);       // g=1 at lane u+4
    float gg = __shfl(red, lane + 2, 64);       // g=2 at lane u+2
    float go = __shfl(red, lane + 6, 64);       // g=3 at lane u+6

    if (lane < 2) {
      const int tt = dir ? (T_LEN - 1 - t) : t;
      gi += xgc0; gf += xgc1; gg += xgc2; go += xgc3;
      float i_ = 1.f / (1.f + __expf(-gi));
      float f_ = 1.f / (1.f + __expf(-gf));
      float g_ = fast_tanh(gg);
      float o_ = 1.f / (1.f + __expf(-go));
      c_state = f_ * c_state + i_ * g_;
      float hn = o_ * fast_tanh(c_state);
      ull packed = ((ull)(unsigned)(t + 2) << 32) | (ull)__float_as_uint(hn);
      __hip_atomic_store(&hb[(((t + 1) & 1) ? 1024 : 0) + jj], packed,
                         __ATOMIC_RELAXED, __HIP_MEMORY_SCOPE_AGENT);
      const int col = dir * 1024 + jj;
      if (outb) outb[(size_t)tt * 2048 + col] = f2b(hn);
      if (outf) outf[(size_t)tt * 2048 + col] = hn;
    }

    xgc0 = xgn0; xgc1 = xgn1; xgc2 = xgn2; xgc3 = xgn3;
  }
}

// out[t][tag] = h1[t]·w_out[tag] + b_out[tag]
__global__ void out_proj(const float* __restrict__ h1, const float* __restrict__ w,
                         const float* __restrict__ b, float* __restrict__ out) {
  int t = blockIdx.x;
  int tag = threadIdx.x;
  if (tag >= 50) return;
  const float4* hp = (const float4*)(h1 + (size_t)t * 2048);
  const float4* wp = (const float4*)(w + (size_t)tag * 2048);
  float acc = 0.f;
#pragma unroll 8
  for (int i = 0; i < 512; ++i) {
    float4 a = hp[i], c = wp[i];
    acc += a.x * c.x + a.y * c.y + a.z * c.z + a.w * c.w;
  }
  out[t * 50 + tag] = acc + b[tag];
}

extern "C" void kernel_launch(void* const* d_in, const int* in_sizes, int n_in,
                              void* d_out, int out_size, void* d_ws, size_t ws_size,
                              hipStream_t stream) {
  (void)in_sizes; (void)n_in; (void)out_size; (void)ws_size;
  const float* sent  = (const float*)d_in[0];
  const int*   stags = (const int*)  d_in[1];
  const float* embsp = (const float*)d_in[2];
  const float* wih0  = (const float*)d_in[3];
  const float* whh0  = (const float*)d_in[4];
  const float* bih0  = (const float*)d_in[5];
  const float* bhh0  = (const float*)d_in[6];
  const float* wih1  = (const float*)d_in[7];
  const float* whh1  = (const float*)d_in[8];
  const float* bih1  = (const float*)d_in[9];
  const float* bhh1  = (const float*)d_in[10];
  const float* wout  = (const float*)d_in[11];
  const float* bout  = (const float*)d_in[12];
  float* out = (float*)d_out;

  char* ws = (char*)d_ws;
  size_t off = 0;
  auto take = [&](size_t bytes) { char* p = ws + off; off += (bytes + 255) & ~(size_t)255; return p; };
  float*          xp    = (float*)         take((size_t)2048 * 8192 * 4);  // shared by both layers
  unsigned short* embB  = (unsigned short*)take((size_t)2048 * 1088 * 2);
  unsigned short* w0B   = (unsigned short*)take((size_t)8192 * 1088 * 2);
  unsigned short* w1B   = (unsigned short*)take((size_t)8192 * 2048 * 2);
  unsigned short* h0B   = (unsigned short*)take((size_t)2048 * 2048 * 2);
  float*          h1F   = (float*)         take((size_t)2048 * 2048 * 4);
  float*          bs0   = (float*)         take(8192 * 4);
  float*          bs1   = (float*)         take(8192 * 4);
  ull*            hbufA = (ull*)           take(2 * 2 * 1024 * 8);
  ull*            hbufB = (ull*)           take(2 * 2 * 1024 * 8);
  // harness poisons ws to 0xAA -> stale tags are 0xAAAAAAAA, never a live
  // tag (1..2050), so hbuf needs no zero-init pass.

  embed_k<<<8704, 256, 0, stream>>>(sent, stags, embsp, embB);
  cvt_k<<<8704, 256, 0, stream>>>(wih0, w0B, 2228224);    // 8192*1088/4
  cvt_k<<<16384, 256, 0, stream>>>(wih1, w1B, 4194304);   // 8192*2048/4
  bias_k<<<32, 256, 0, stream>>>(bih0, bhh0, bs0);
  bias_k<<<32, 256, 0, stream>>>(bih1, bhh1, bs1);

  dim3 gg(128, 32);
  gemm_bf16<<<gg, 256, 0, stream>>>(embB, w0B, bs0, xp, 8192, 1088);
  lstm_scan<<<128, 512, 0, stream>>>(xp, whh0, h0B, nullptr, hbufA);
  gemm_bf16<<<gg, 256, 0, stream>>>(h0B, w1B, bs1, xp, 8192, 2048);
  lstm_scan<<<128, 512, 0, stream>>>(xp, whh1, nullptr, h1F, hbufB);
  out_proj<<<2048, 64, 0, stream>>>(h1F, wout, bout, out);
}